// Round 4
// baseline (604.361 us; speedup 1.0000x reference)
//
#include <hip/hip_runtime.h>
#include <stdint.h>

// DoomLiquidNet: conv(3->32,k4s2p1) -> conv(32->64,k4s2p1) -> CfC core -> logits
// Inputs f32 (detected on device; bf16 fallback kept). Compute in bf16 MFMA.
//
// R10: ISOLATED TEST: k_convs launch_bounds (256,4) -> (256,8).
//   Evidence: measured occupancy == 2nd-arg waves/EU in R6/R7/R9 even when
//   LDS+VGPR allow more (R9: 7 blocks fit, 52 VGPR, yet occ pinned at 43.6%).
//   Hypothesis: waves-per-eu attr pins resident waves. (256,8) caps VGPR at
//   64 >= 52 actually needed -> no spill (R7's spill was 512thr: demand ~90 > 64).
// R9/R8: k_convs QUARTER-IMAGE blocks, 256 threads (grid 8192, one block = 4
//   conv2 output rows). LDS 20768B -> 7 blocks/CU possible.
//   k_xb: M-tile 32, grid (64,16).
//
// ws layout:
//   xbp   : f32  [16][2048][128]     @ 0           16777216 B
//   feats : bf16 [2048][16384]       @ 150994944   67108864 B
//   bbT   : bf16 [128][16448]        @ 218103808    4210688 B
//   HT    : bf16 [256][128]          @ 222314496      65536 B
//   w1p   : bf16 [32][64]            @ 222380032       4096 B
//   w2c   : bf16 [64][512]           @ 222384128      65536 B
//   xb    : f32  [2048][128]         @ 222449664    1048576 B
//   rout  : f32  [2048][64]          @ 223498240     524288 B
//   consts: f32  [3048]              @ 224022528      12288 B
//   flag  : int                      @ 224034816          4 B

typedef unsigned short u16;
typedef unsigned int u32;

typedef float f32x4 __attribute__((ext_vector_type(4)));
typedef short s16x8 __attribute__((ext_vector_type(8)));
typedef __bf16 b16x8 __attribute__((ext_vector_type(8)));

template <typename V>
__device__ inline auto mfma_sel(V a, V b, f32x4 c, int)
    -> decltype(__builtin_amdgcn_mfma_f32_16x16x32_bf16(a, b, c, 0, 0, 0)) {
  return __builtin_amdgcn_mfma_f32_16x16x32_bf16(a, b, c, 0, 0, 0);
}
template <typename V>
__device__ inline f32x4 mfma_sel(V a, V b, f32x4 c, long) {
  union UU { V s; b16x8 b; };
  UU ua; ua.s = a;
  UU ub; ub.s = b;
  return __builtin_amdgcn_mfma_f32_16x16x32_bf16(ua.b, ub.b, c, 0, 0, 0);
}
__device__ inline f32x4 mfma16x16x32(s16x8 a, s16x8 b, f32x4 c) {
  return mfma_sel(a, b, c, 0);
}

__device__ inline float bf2f(u16 v) {
  union { u32 i; float f; } x; x.i = ((u32)v) << 16; return x.f;
}
__device__ inline u16 f2bf(float f) {  // round-to-nearest-even
  union { float f; u32 i; } x; x.f = f;
  u32 i = x.i;
  i += 0x7fffu + ((i >> 16) & 1u);
  return (u16)(i >> 16);
}
__device__ inline void bf2x2(u32 u, float& lo, float& hi) {
  union { u32 i; float f; } a, b;
  a.i = u << 16; b.i = u & 0xffff0000u;
  lo = a.f; hi = b.f;
}
__device__ inline float ldf(int isbf, const void* p, size_t i) {
  return isbf ? bf2f(((const u16*)p)[i]) : ((const float*)p)[i];
}
__device__ inline u16 ldb(int isbf, const void* p, size_t i) {
  return isbf ? ((const u16*)p)[i] : f2bf(((const float*)p)[i]);
}
__device__ inline float fast_tanh(float x) {
  float ax = fabsf(x);
  float e = __expf(2.0f * ax);
  float t = 1.0f - 2.0f / (e + 1.0f);
  return copysignf(t, x);
}

// ---------- fused prep: detect + consts + w1p + w2c + bbT + HT ----------
__global__ __launch_bounds__(256)
void k_prep_all(const u32* __restrict__ bwords,
                const void* b1, const void* b2, const void* bbb,
                const void* f1b, const void* f2b, const void* tab,
                const void* tbb, const void* oww, const void* obb,
                const void* hx, const void* w1, const void* w2,
                const void* bw, const void* f1w, const void* f2w,
                const void* taw, const void* tbw,
                float* __restrict__ consts, u16* __restrict__ w1p,
                u16* __restrict__ w2c, u16* __restrict__ bbT,
                u16* __restrict__ HT, int* __restrict__ flag) {
  __shared__ u16 t[64][65];
  const int tid = threadIdx.x;
  const int b = blockIdx.x;
  const u32 wd = bwords[tid & 63];
  const u32 ex = (wd >> 7) & 0xFFu;
  unsigned long long m = __ballot(ex >= 100u && ex <= 126u);
  const int isbf = (__popcll(m) >= 32) ? 1 : 0;
  if (b == 0 && tid == 0) *flag = isbf;

  if (b < 12) {
    const int e = b * 256 + tid;
    if (e >= 3048) return;
    float v;
    if (e < 32)        v = ldf(isbf, b1, e);
    else if (e < 96)   v = ldf(isbf, b2, e - 32);
    else if (e < 224)  v = ldf(isbf, bbb, e - 96);
    else if (e < 288)  v = ldf(isbf, f1b, e - 224);
    else if (e < 352)  v = ldf(isbf, f2b, e - 288);
    else if (e < 416)  v = ldf(isbf, tab, e - 352);
    else if (e < 480)  v = ldf(isbf, tbb, e - 416);
    else if (e < 992)  v = ldf(isbf, oww, e - 480);
    else if (e < 1000) v = ldf(isbf, obb, e - 992);
    else               v = ldf(isbf, hx, e - 1000);
    consts[e] = v;
  } else if (b < 20) {
    const int e = (b - 12) * 256 + tid;
    const int k = e & 63, co = e >> 6;
    w1p[e] = (k < 48) ? ldb(isbf, w1, co * 48 + k) : (u16)0;
  } else if (b < 148) {
    const int e = (b - 20) * 256 + tid;
    w2c[e] = ldb(isbf, w2, e);
  } else if (b < 662) {
    const int idx = b - 148;
    const int k0 = (idx >> 1) * 64, j0 = (idx & 1) * 64;
    #pragma unroll
    for (int i = 0; i < 16; ++i) {
      int e = tid + 256 * i;
      int kl = e >> 6, jl = e & 63;
      t[kl][jl] = ldb(isbf, bw, (size_t)(k0 + kl) * 128 + j0 + jl);
    }
    __syncthreads();
    #pragma unroll
    for (int i = 0; i < 16; ++i) {
      int e = tid + 256 * i;
      int jl = e >> 6, kl = e & 63;
      bbT[(size_t)(j0 + jl) * 16448 + k0 + kl] = t[kl][jl];
    }
  } else {
    const int idx = b - 662;
    const int h = idx >> 1, i0 = (idx & 1) * 64;
    const void* W = (h == 0) ? f1w : (h == 1) ? f2w : (h == 2) ? taw : tbw;
    #pragma unroll
    for (int i = 0; i < 16; ++i) {
      int e = tid + 256 * i;
      int il = e >> 6, cl = e & 63;
      t[il][cl] = ldb(isbf, W, (i0 + il) * 64 + cl);
    }
    __syncthreads();
    #pragma unroll
    for (int i = 0; i < 16; ++i) {
      int e = tid + 256 * i;
      int cl = e >> 6, il = e & 63;
      HT[(h * 64 + cl) * 128 + i0 + il] = t[il][cl];
    }
  }
}

// ---------- fused conv1+conv2, QUARTER-IMAGE blocks ----------
// block = (n = bx>>2, q = bx&3); q selects conv2 output rows [4q, 4q+4).
// a1 rows needed (padded): ja=0..9 <-> global a1 row ja + 8q - 1.
// x rows needed: local lx=0..21 <-> global x row lx + xbase,
//   xbase = (q==0) ? -1 : 16q-3; out-of-range rows staged as zeros.
// conv1 tile j (real a1 rows): ja = j + (q==0), x row pair at lx = 2j+khb.
// LDS u32 map (contiguous):
//   XS   @ 0    : 3 planes x 22 rows x 34 u32 (shifted-pair)   2244
//   ZS   @ 2244 : 68 u32 zeros (conv1 K-pad plane reads)         68
//   A1H  @ 2312 : 16 planes x 10 rows x 18 u32 (shifted-pair)  2880
//   total 5192 u32 = 20768 B -> 7 blocks/CU
__global__ __launch_bounds__(256, 8)
void k_convs(const int* __restrict__ flagp, const void* __restrict__ x,
             const u16* __restrict__ w1p, const u16* __restrict__ w2c,
             const float* __restrict__ consts, u16* __restrict__ feats) {
  __shared__ u32 lx[5192];
  const int isbf = *flagp;
  const int n = blockIdx.x >> 2;
  const int q = blockIdx.x & 3;
  const int tid = threadIdx.x;
  const int wv = tid >> 6, lane = tid & 63, quad = lane >> 4, l15 = lane & 15;

  // zero: ZS + whole A1H (disjoint from staging)
  for (int e = tid; e < 2948; e += 256) lx[2244 + e] = 0u;

  // stage x local rows 0..21 -> XS, shifted-pair bf16; OOB rows = zeros
  const int xbase = (q == 0) ? -1 : 16 * q - 3;
  for (int e = tid; e < 1056; e += 256) {  // 3 planes * 22 rows * 16 tt
    const int rt = e >> 4;
    const int tt = e & 15;
    const int ci = rt / 22;
    const int rl = rt - ci * 22;
    const int gx = rl + xbase;
    u32* dst = &lx[(ci * 22 + rl) * 34];
    if (gx < 0 || gx > 63) {
      dst[2 * tt] = 0u; dst[2 * tt + 1] = 0u;
      if (tt == 15) { dst[32] = 0u; dst[33] = 0u; }
    } else if (!isbf) {
      const float* src = (const float*)x + (((size_t)n * 3 + ci) * 64 + gx) * 64 + 4 * tt;
      const f32x4 v = *(const f32x4*)src;
      const float pv = tt ? src[-1] : 0.f;
      dst[2 * tt]     = (u32)f2bf(pv)   | (((u32)f2bf(v[0])) << 16);
      dst[2 * tt + 1] = (u32)f2bf(v[1]) | (((u32)f2bf(v[2])) << 16);
      if (tt == 15) { dst[32] = (u32)f2bf(v[3]); dst[33] = 0u; }
    } else {
      const u16* src = (const u16*)x + (((size_t)n * 3 + ci) * 64 + gx) * 64 + 4 * tt;
      const u16 pv = tt ? src[-1] : (u16)0;
      dst[2 * tt]     = (u32)pv | (((u32)src[0]) << 16);
      dst[2 * tt + 1] = (u32)src[1] | (((u32)src[2]) << 16);
      if (tt == 15) { dst[32] = (u32)src[3]; dst[33] = 0u; }
    }
  }
  __syncthreads();

  f32x4 acc2[4];
  #pragma unroll
  for (int mt = 0; mt < 4; ++mt) acc2[mt] = f32x4{0.f, 0.f, 0.f, 0.f};

  const int khb = (quad & 1) * 2;
  const int cih = quad >> 1;
  u16* lp = (u16*)lx;
  const int nA = (q == 0 || q == 3) ? 9 : 10;   // real a1 rows in this block
  const int ntiles = 2 * nA;
  const int joff = (q == 0) ? 1 : 0;

  #pragma unroll
  for (int h = 0; h < 2; ++h) {
    // ---- conv1: real a1 rows -> A1H, co = h*16 .. h*16+15 ----
    const s16x8 af0 = *(const s16x8*)(w1p + (h * 16 + l15) * 64 + quad * 8);
    const s16x8 af1 = *(const s16x8*)(w1p + (h * 16 + l15) * 64 + 32 + quad * 8);
    #pragma unroll
    for (int i = 0; i < 5; ++i) {
      const int nt = wv + 4 * i;   // up to 20 tiles = 10 rows x 2 col-blocks
      if (nt < ntiles) {
        const int j = nt >> 1;
        const int ob = (nt & 1) * 16;
        const int r1 = 2 * j + khb;      // local staged-x row
        f32x4 a1acc = f32x4{0.f, 0.f, 0.f, 0.f};
        {
          const int base = (cih * 22 + r1) * 34 + ob + l15;
          union { u32 u[4]; s16x8 v; } bf;
          bf.u[0] = lx[base];
          bf.u[1] = lx[base + 1];
          bf.u[2] = lx[base + 34];
          bf.u[3] = lx[base + 35];
          a1acc = mfma16x16x32(af0, bf.v, a1acc);
        }
        {
          // ci1 = 2+cih: plane 2 real, plane 3 = K-pad -> zero strip
          const int base = (cih == 0) ? ((2 * 22 + r1) * 34 + ob + l15)
                                      : (2244 + ob + l15);
          union { u32 u[4]; s16x8 v; } bf;
          bf.u[0] = lx[base];
          bf.u[1] = lx[base + 1];
          bf.u[2] = lx[base + 34];
          bf.u[3] = lx[base + 35];
          a1acc = mfma16x16x32(af1, bf.v, a1acc);
        }
        const int ja = j + joff;         // A1H padded-local row
        #pragma unroll
        for (int r = 0; r < 4; ++r) {
          const int co = quad * 4 + r;
          float v = a1acc[r] + consts[h * 16 + co];
          v = v > 0.f ? v : 0.f;
          lp[(2312 + co * 180 + ja * 18) * 2 + ob + l15 + 1] = f2bf(v);
        }
      }
    }
    __syncthreads();  // a1 half ready
    // ---- conv2 K-half: planes 16h..16h+15, local output row wv ----
    #pragma unroll
    for (int kst = 0; kst < 8; ++kst) {
      const int kglob = h * 8 + kst;
      s16x8 afr[4];
      #pragma unroll
      for (int mt = 0; mt < 4; ++mt)
        afr[mt] = *(const s16x8*)(w2c + (mt * 16 + l15) * 512 + kglob * 32 + quad * 8);
      const int ci = kst * 2 + cih;
      const int base = 2312 + ci * 180 + (2 * wv + khb) * 18 + l15;
      union { u32 u[4]; s16x8 v; } bf;
      bf.u[0] = lx[base];
      bf.u[1] = lx[base + 1];
      bf.u[2] = lx[base + 18];
      bf.u[3] = lx[base + 19];
      #pragma unroll
      for (int mt = 0; mt < 4; ++mt)
        acc2[mt] = mfma16x16x32(afr[mt], bf.v, acc2[mt]);
    }
    if (h == 0) __syncthreads();  // conv2 h0 done reading before conv1 h1 writes
  }
  // ---- epilogue: feats ----
  const int oh = q * 4 + wv;
  #pragma unroll
  for (int mt = 0; mt < 4; ++mt)
    #pragma unroll
    for (int r = 0; r < 4; ++r) {
      const int co = mt * 16 + quad * 4 + r;
      float v = acc2[mt][r] + consts[32 + co];
      v = v > 0.f ? v : 0.f;
      feats[(size_t)n * 16384 + co * 256 + oh * 16 + l15] = f2bf(v);
    }
}

// ---------- xb partials: feats @ bb_w[:16384], split-K=16, M-tile=32 ------
__global__ __launch_bounds__(256)
void k_xb(const u16* __restrict__ feats, const u16* __restrict__ bbT,
          float* __restrict__ xbp) {
  const int m0 = blockIdx.x * 32;
  const int kc = blockIdx.y;
  const int kc0 = kc * 1024;
  const int tid = threadIdx.x;
  const int w = tid >> 6, lane = tid & 63, quad = lane >> 4, l15 = lane & 15;
  f32x4 acc[2][2];
  #pragma unroll
  for (int mt = 0; mt < 2; ++mt)
    #pragma unroll
    for (int i = 0; i < 2; ++i) acc[mt][i] = f32x4{0.f, 0.f, 0.f, 0.f};
  #pragma unroll 4
  for (int kst = 0; kst < 32; ++kst) {
    const int k = kc0 + kst * 32 + quad * 8;
    s16x8 afrag[2], bfrag[2];
    #pragma unroll
    for (int mt = 0; mt < 2; ++mt)
      afrag[mt] = *(const s16x8*)(feats + (size_t)(m0 + mt * 16 + l15) * 16384 + k);
    #pragma unroll
    for (int i = 0; i < 2; ++i)
      bfrag[i] = *(const s16x8*)(bbT + (size_t)((w * 2 + i) * 16 + l15) * 16448 + k);
    #pragma unroll
    for (int mt = 0; mt < 2; ++mt)
      #pragma unroll
      for (int i = 0; i < 2; ++i)
        acc[mt][i] = mfma16x16x32(afrag[mt], bfrag[i], acc[mt][i]);
  }
  float* dst = xbp + (size_t)kc * 262144;
  #pragma unroll
  for (int mt = 0; mt < 2; ++mt)
    #pragma unroll
    for (int i = 0; i < 2; ++i) {
      const int j = (w * 2 + i) * 16 + l15;
      #pragma unroll
      for (int r = 0; r < 4; ++r) {
        const int m = m0 + mt * 16 + quad * 4 + r;
        dst[m * 128 + j] = acc[mt][i][r];
      }
    }
}

// ---------- reduce split-K partials -> xb ----------
__global__ __launch_bounds__(256)
void k_xbsum(const float* __restrict__ xbp, float* __restrict__ xb) {
  const int e = blockIdx.x * 256 + threadIdx.x;
  float s = 0.f;
  #pragma unroll
  for (int kc = 0; kc < 16; ++kc) s += xbp[(size_t)kc * 262144 + e];
  xb[e] = s;
}

// ---------- CfC recurrence: one block per batch row, 3 barriers/step ----------
__global__ __launch_bounds__(256)
void k_rec(const int* __restrict__ flagp, const float* __restrict__ xb,
           const u16* __restrict__ bbT, const u16* __restrict__ HT,
           const float* __restrict__ consts, float* __restrict__ rout,
           void* __restrict__ outv) {
  __shared__ float xbl[64 * 128];
  __shared__ float h[64];
  __shared__ float bbv[128];
  __shared__ float heads[256];
  const int isbf = *flagp;
  const int b = blockIdx.x;
  const int tid = threadIdx.x;
  {
    const float* src = xb + (size_t)b * 64 * 128;
    #pragma unroll
    for (int q = 0; q < 32; ++q) xbl[q * 256 + tid] = src[q * 256 + tid];
  }
  // phase-1 weights: full K=64 column for j = tid (threads 0..127)
  float w1r[64];
  if (tid < 128) {
    const u32* src = (const u32*)(bbT + (size_t)tid * 16448 + 16384);
    #pragma unroll
    for (int q = 0; q < 32; ++q) bf2x2(src[q], w1r[2 * q], w1r[2 * q + 1]);
  }
  float w2r[128];
  {
    const u32* src = (const u32*)(HT + tid * 128);
    #pragma unroll
    for (int q = 0; q < 64; ++q) bf2x2(src[q], w2r[2 * q], w2r[2 * q + 1]);
  }
  const float hbias = consts[224 + tid];
  const float bbias = (tid < 128) ? consts[96 + tid] : 0.f;
  if (tid < 64) h[tid] = consts[1000 + b * 64 + tid];
  __syncthreads();
  for (int t = 0; t < 64; ++t) {
    if (tid < 128) {
      float p0 = 0.f, p1 = 0.f, p2 = 0.f, p3 = 0.f;
      #pragma unroll
      for (int q = 0; q < 16; ++q) {
        p0 += h[4 * q + 0] * w1r[4 * q + 0];
        p1 += h[4 * q + 1] * w1r[4 * q + 1];
        p2 += h[4 * q + 2] * w1r[4 * q + 2];
        p3 += h[4 * q + 3] * w1r[4 * q + 3];
      }
      const float s = (p0 + p1) + (p2 + p3) + xbl[t * 128 + tid] + bbias;
      bbv[tid] = 1.7159f * fast_tanh(0.666f * s);
    }
    __syncthreads();
    float c0 = 0.f, c1 = 0.f, c2 = 0.f, c3 = 0.f;
    #pragma unroll
    for (int q = 0; q < 32; ++q) {
      c0 += bbv[4 * q + 0] * w2r[4 * q + 0];
      c1 += bbv[4 * q + 1] * w2r[4 * q + 1];
      c2 += bbv[4 * q + 2] * w2r[4 * q + 2];
      c3 += bbv[4 * q + 3] * w2r[4 * q + 3];
    }
    heads[tid] = (c0 + c1) + (c2 + c3) + hbias;
    __syncthreads();
    if (tid < 64) {
      const float ff1 = fast_tanh(heads[tid]);
      const float ff2 = fast_tanh(heads[64 + tid]);
      const float ti = 1.f / (1.f + __expf(-(heads[128 + tid] + heads[192 + tid])));
      const float hn = ff1 * (1.f - ti) + ti * ff2;
      h[tid] = hn;
      rout[((size_t)b * 64 + t) * 64 + tid] = hn;
    }
    __syncthreads();
  }
  if (tid < 64) {
    if (isbf) ((u16*)outv)[16384 + b * 64 + tid] = f2bf(h[tid]);
    else      ((float*)outv)[16384 + b * 64 + tid] = h[tid];
  }
}

// ---------- logits = rout @ out_w + out_b ----------
__global__ __launch_bounds__(256)
void k_logits(const int* __restrict__ flagp, const float* __restrict__ rout,
              const float* __restrict__ consts, void* __restrict__ outv) {
  __shared__ float W[512];
  __shared__ float Bv[8];
  const int isbf = *flagp;
  const int tid = threadIdx.x;
  for (int e = tid; e < 512; e += 256) W[e] = consts[480 + e];
  if (tid < 8) Bv[tid] = consts[992 + tid];
  __syncthreads();
  const int bt = blockIdx.x * 256 + tid;
  float acc[8];
  #pragma unroll
  for (int c = 0; c < 8; ++c) acc[c] = Bv[c];
  const f32x4* r = (const f32x4*)(rout + (size_t)bt * 64);
  #pragma unroll
  for (int q = 0; q < 16; ++q) {
    f32x4 v = r[q];
    #pragma unroll
    for (int u = 0; u < 4; ++u) {
      const float rv = v[u];
      const int i = 4 * q + u;
      #pragma unroll
      for (int c = 0; c < 8; ++c) acc[c] += rv * W[i * 8 + c];
    }
  }
  if (isbf) {
    u32 pk[4];
    #pragma unroll
    for (int c = 0; c < 4; ++c)
      pk[c] = (u32)f2bf(acc[2 * c]) | ((u32)f2bf(acc[2 * c + 1]) << 16);
    *(uint4*)((u16*)outv + (size_t)bt * 8) = *(const uint4*)pk;
  } else {
    float* o = (float*)outv + (size_t)bt * 8;
    *(f32x4*)o = f32x4{acc[0], acc[1], acc[2], acc[3]};
    *(f32x4*)(o + 4) = f32x4{acc[4], acc[5], acc[6], acc[7]};
  }
}

extern "C" void kernel_launch(void* const* d_in, const int* in_sizes, int n_in,
                              void* d_out, int out_size, void* d_ws, size_t ws_size,
                              hipStream_t stream) {
  const void* x   = d_in[0];
  const void* hx  = d_in[1];
  const void* w1  = d_in[2];
  const void* b1  = d_in[3];
  const void* w2  = d_in[4];
  const void* b2  = d_in[5];
  const void* bbw = d_in[6];
  const void* bbb = d_in[7];
  const void* f1w = d_in[8];
  const void* f1b = d_in[9];
  const void* f2w = d_in[10];
  const void* f2b = d_in[11];
  const void* taw = d_in[12];
  const void* tab = d_in[13];
  const void* tbw = d_in[14];
  const void* tbb = d_in[15];
  const void* oww = d_in[16];
  const void* obb = d_in[17];

  char* ws = (char*)d_ws;
  float* xbp   = (float*)(ws);
  u16*   feats = (u16*)(ws + 150994944);
  u16*   bbT   = (u16*)(ws + 218103808);
  u16*   HT    = (u16*)(ws + 222314496);
  u16*   w1p   = (u16*)(ws + 222380032);
  u16*   w2c   = (u16*)(ws + 222384128);
  float* xb    = (float*)(ws + 222449664);
  float* rout  = (float*)(ws + 223498240);
  float* consts= (float*)(ws + 224022528);
  int*   flag  = (int*)(ws + 224034816);

  k_prep_all<<<670, 256, 0, stream>>>((const u32*)bbw, b1, b2, bbb, f1b, f2b,
                                      tab, tbb, oww, obb, hx, w1, w2, bbw,
                                      f1w, f2w, taw, tbw,
                                      consts, w1p, w2c, bbT, HT, flag);
  k_convs<<<8192, 256, 0, stream>>>(flag, x, w1p, w2c, consts, feats);
  k_xb<<<dim3(64, 16), 256, 0, stream>>>(feats, bbT, xbp);
  k_xbsum<<<1024, 256, 0, stream>>>(xbp, xb);
  k_rec<<<32, 256, 0, stream>>>(flag, xb, bbT, HT, consts, rout, d_out);
  k_logits<<<8, 256, 0, stream>>>(flag, rout, consts, d_out);
}

// Round 5
// 604.210 us; speedup vs baseline: 1.0002x; 1.0002x over previous
//
#include <hip/hip_runtime.h>
#include <stdint.h>

// DoomLiquidNet: conv(3->32,k4s2p1) -> conv(32->64,k4s2p1) -> CfC core -> logits
// Inputs f32 (detected on device; bf16 fallback kept). Compute in bf16 MFMA.
//
// R11: half-image 512-thr k_convs (R7 geometry) with __launch_bounds__(512,6).
//   Empirical law from R0..R10: resident blocks/CU caps at ~4 regardless of
//   LDS/VGPR headroom -> only 512-thr blocks can reach 32 waves/CU.
//   R7 proved 4x36KB blocks go resident (occ 88%) but (512,8) capped VGPR at
//   64 < demand (~70) -> 440MB scratch spill. (512,6) caps at ~80 >= demand
//   (R9 measured 52-60 for the same per-thread body) -> no spill + 24-32 waves.
// R9 lesson: 256-thr blocks pin at ~3.5 blk x 4 waves = 14 waves/CU (worse),
//   and 4x per-block overhead. Reverted.
//
// ws layout:
//   xbp   : f32  [16][2048][128]     @ 0           16777216 B
//   feats : bf16 [2048][16384]       @ 150994944   67108864 B
//   bbT   : bf16 [128][16448]        @ 218103808    4210688 B
//   HT    : bf16 [256][128]          @ 222314496      65536 B
//   w1p   : bf16 [32][64]            @ 222380032       4096 B
//   w2c   : bf16 [64][512]           @ 222384128      65536 B
//   xb    : f32  [2048][128]         @ 222449664    1048576 B
//   rout  : f32  [2048][64]          @ 223498240     524288 B
//   consts: f32  [3048]              @ 224022528      12288 B
//   flag  : int                      @ 224034816          4 B

typedef unsigned short u16;
typedef unsigned int u32;

typedef float f32x4 __attribute__((ext_vector_type(4)));
typedef short s16x8 __attribute__((ext_vector_type(8)));
typedef __bf16 b16x8 __attribute__((ext_vector_type(8)));

template <typename V>
__device__ inline auto mfma_sel(V a, V b, f32x4 c, int)
    -> decltype(__builtin_amdgcn_mfma_f32_16x16x32_bf16(a, b, c, 0, 0, 0)) {
  return __builtin_amdgcn_mfma_f32_16x16x32_bf16(a, b, c, 0, 0, 0);
}
template <typename V>
__device__ inline f32x4 mfma_sel(V a, V b, f32x4 c, long) {
  union UU { V s; b16x8 b; };
  UU ua; ua.s = a;
  UU ub; ub.s = b;
  return __builtin_amdgcn_mfma_f32_16x16x32_bf16(ua.b, ub.b, c, 0, 0, 0);
}
__device__ inline f32x4 mfma16x16x32(s16x8 a, s16x8 b, f32x4 c) {
  return mfma_sel(a, b, c, 0);
}

__device__ inline float bf2f(u16 v) {
  union { u32 i; float f; } x; x.i = ((u32)v) << 16; return x.f;
}
__device__ inline u16 f2bf(float f) {  // round-to-nearest-even
  union { float f; u32 i; } x; x.f = f;
  u32 i = x.i;
  i += 0x7fffu + ((i >> 16) & 1u);
  return (u16)(i >> 16);
}
__device__ inline void bf2x2(u32 u, float& lo, float& hi) {
  union { u32 i; float f; } a, b;
  a.i = u << 16; b.i = u & 0xffff0000u;
  lo = a.f; hi = b.f;
}
__device__ inline float ldf(int isbf, const void* p, size_t i) {
  return isbf ? bf2f(((const u16*)p)[i]) : ((const float*)p)[i];
}
__device__ inline u16 ldb(int isbf, const void* p, size_t i) {
  return isbf ? ((const u16*)p)[i] : f2bf(((const float*)p)[i]);
}
__device__ inline float fast_tanh(float x) {
  float ax = fabsf(x);
  float e = __expf(2.0f * ax);
  float t = 1.0f - 2.0f / (e + 1.0f);
  return copysignf(t, x);
}

// ---------- fused prep: detect + consts + w1p + w2c + bbT + HT ----------
__global__ __launch_bounds__(256)
void k_prep_all(const u32* __restrict__ bwords,
                const void* b1, const void* b2, const void* bbb,
                const void* f1b, const void* f2b, const void* tab,
                const void* tbb, const void* oww, const void* obb,
                const void* hx, const void* w1, const void* w2,
                const void* bw, const void* f1w, const void* f2w,
                const void* taw, const void* tbw,
                float* __restrict__ consts, u16* __restrict__ w1p,
                u16* __restrict__ w2c, u16* __restrict__ bbT,
                u16* __restrict__ HT, int* __restrict__ flag) {
  __shared__ u16 t[64][65];
  const int tid = threadIdx.x;
  const int b = blockIdx.x;
  const u32 wd = bwords[tid & 63];
  const u32 ex = (wd >> 7) & 0xFFu;
  unsigned long long m = __ballot(ex >= 100u && ex <= 126u);
  const int isbf = (__popcll(m) >= 32) ? 1 : 0;
  if (b == 0 && tid == 0) *flag = isbf;

  if (b < 12) {
    const int e = b * 256 + tid;
    if (e >= 3048) return;
    float v;
    if (e < 32)        v = ldf(isbf, b1, e);
    else if (e < 96)   v = ldf(isbf, b2, e - 32);
    else if (e < 224)  v = ldf(isbf, bbb, e - 96);
    else if (e < 288)  v = ldf(isbf, f1b, e - 224);
    else if (e < 352)  v = ldf(isbf, f2b, e - 288);
    else if (e < 416)  v = ldf(isbf, tab, e - 352);
    else if (e < 480)  v = ldf(isbf, tbb, e - 416);
    else if (e < 992)  v = ldf(isbf, oww, e - 480);
    else if (e < 1000) v = ldf(isbf, obb, e - 992);
    else               v = ldf(isbf, hx, e - 1000);
    consts[e] = v;
  } else if (b < 20) {
    const int e = (b - 12) * 256 + tid;
    const int k = e & 63, co = e >> 6;
    w1p[e] = (k < 48) ? ldb(isbf, w1, co * 48 + k) : (u16)0;
  } else if (b < 148) {
    const int e = (b - 20) * 256 + tid;
    w2c[e] = ldb(isbf, w2, e);
  } else if (b < 662) {
    const int idx = b - 148;
    const int k0 = (idx >> 1) * 64, j0 = (idx & 1) * 64;
    #pragma unroll
    for (int i = 0; i < 16; ++i) {
      int e = tid + 256 * i;
      int kl = e >> 6, jl = e & 63;
      t[kl][jl] = ldb(isbf, bw, (size_t)(k0 + kl) * 128 + j0 + jl);
    }
    __syncthreads();
    #pragma unroll
    for (int i = 0; i < 16; ++i) {
      int e = tid + 256 * i;
      int jl = e >> 6, kl = e & 63;
      bbT[(size_t)(j0 + jl) * 16448 + k0 + kl] = t[kl][jl];
    }
  } else {
    const int idx = b - 662;
    const int h = idx >> 1, i0 = (idx & 1) * 64;
    const void* W = (h == 0) ? f1w : (h == 1) ? f2w : (h == 2) ? taw : tbw;
    #pragma unroll
    for (int i = 0; i < 16; ++i) {
      int e = tid + 256 * i;
      int il = e >> 6, cl = e & 63;
      t[il][cl] = ldb(isbf, W, (i0 + il) * 64 + cl);
    }
    __syncthreads();
    #pragma unroll
    for (int i = 0; i < 16; ++i) {
      int e = tid + 256 * i;
      int cl = e >> 6, il = e & 63;
      HT[(h * 64 + cl) * 128 + i0 + il] = t[il][cl];
    }
  }
}

// ---------- fused conv1+conv2, HALF-IMAGE blocks, 512 thr ----------
// block = (n = bx>>1, rh = bx&1); rh selects conv2 output rows [8rh, 8rh+8).
// LDS u32 map:
//   XS   @ 0    : 3 planes x 36 rows x 34 u32 (shifted-pair; local row l =
//                 padded-global row l + 30*rh; border row zeroed)
//   ZS   @ 3672 : 68 u32 zeros (conv1 K-pad plane reads)
//   A1H  @ 3740 : 16 planes x 18 rows x 18 u32 (local row = a1row + 1 - 16*rh)
//   total 8924 u32 = 35696 B -> 4 blocks/CU (the empirical blocks/CU cap)
__global__ __launch_bounds__(512, 6)
void k_convs(const int* __restrict__ flagp, const void* __restrict__ x,
             const u16* __restrict__ w1p, const u16* __restrict__ w2c,
             const float* __restrict__ consts, u16* __restrict__ feats) {
  __shared__ u32 lx[8924];
  const int isbf = *flagp;
  const int n = blockIdx.x >> 1;
  const int rh = blockIdx.x & 1;
  const int tid = threadIdx.x;
  const int wv = tid >> 6, lane = tid & 63, quad = lane >> 4, l15 = lane & 15;

  // zero: XS border row (102) + zero strip (68) + whole A1H (5184)
  const int brow = rh ? 35 : 0;
  for (int e = tid; e < 5354; e += 512) {
    int idx;
    if (e < 102) {
      const int pl = e / 34;
      idx = pl * 1224 + brow * 34 + (e - pl * 34);
    } else if (e < 170) {
      idx = 3672 + (e - 102);
    } else {
      idx = 3740 + (e - 170);
    }
    lx[idx] = 0u;
  }
  // stage x rows [29*rh, 29*rh+34] -> XS local rows rl+1-rh, shifted-pair bf16
  for (int e = tid; e < 1680; e += 512) {
    const int rt = e >> 4;        // 0..104 = (ci, rl)
    const int tt = e & 15;
    const int ci = rt / 35;
    const int rl = rt - ci * 35;  // 0..34
    const int rr = rl + 29 * rh;  // source x row
    u32* dst = &lx[(ci * 36 + rl + 1 - rh) * 34];
    if (!isbf) {
      const float* src = (const float*)x + (((size_t)n * 3 + ci) * 64 + rr) * 64 + 4 * tt;
      const f32x4 v = *(const f32x4*)src;
      const float pv = tt ? src[-1] : 0.f;
      dst[2 * tt]     = (u32)f2bf(pv)   | (((u32)f2bf(v[0])) << 16);
      dst[2 * tt + 1] = (u32)f2bf(v[1]) | (((u32)f2bf(v[2])) << 16);
      if (tt == 15) { dst[32] = (u32)f2bf(v[3]); dst[33] = 0u; }
    } else {
      const u16* src = (const u16*)x + (((size_t)n * 3 + ci) * 64 + rr) * 64 + 4 * tt;
      const u16 pv = tt ? src[-1] : (u16)0;
      dst[2 * tt]     = (u32)pv | (((u32)src[0]) << 16);
      dst[2 * tt + 1] = (u32)src[1] | (((u32)src[2]) << 16);
      if (tt == 15) { dst[32] = (u32)src[3]; dst[33] = 0u; }
    }
  }
  __syncthreads();

  f32x4 acc2[4];
  #pragma unroll
  for (int mt = 0; mt < 4; ++mt) acc2[mt] = f32x4{0.f, 0.f, 0.f, 0.f};

  const int khb = (quad & 1) * 2;
  const int cih = quad >> 1;
  u16* lp = (u16*)lx;

  #pragma unroll
  for (int h = 0; h < 2; ++h) {
    // ---- conv1: a1 rows [15*rh, 15*rh+16] for co = h*16 .. h*16+15 -> A1H ----
    const s16x8 af0 = *(const s16x8*)(w1p + (h * 16 + l15) * 64 + quad * 8);
    const s16x8 af1 = *(const s16x8*)(w1p + (h * 16 + l15) * 64 + 32 + quad * 8);
    #pragma unroll
    for (int i = 0; i < 5; ++i) {
      const int nt = wv + 8 * i;   // 34 tiles = 17 rows x 2 col-blocks
      if (nt < 34) {
        const int ohl = nt >> 1;         // local a1 row 0..16
        const int ob = (nt & 1) * 16;
        const int r1 = 2 * ohl + khb;    // local padded-x row (rh-free)
        f32x4 a1acc = f32x4{0.f, 0.f, 0.f, 0.f};
        {
          const int base = (cih * 36 + r1) * 34 + ob + l15;
          union { u32 u[4]; s16x8 v; } bf;
          bf.u[0] = lx[base];
          bf.u[1] = lx[base + 1];
          bf.u[2] = lx[base + 34];
          bf.u[3] = lx[base + 35];
          a1acc = mfma16x16x32(af0, bf.v, a1acc);
        }
        {
          // ci1 = 2+cih: plane 2 real, plane 3 = K-pad -> zero strip
          const int base = (cih == 0) ? ((2 * 36 + r1) * 34 + ob + l15)
                                      : (3672 + ob + l15);
          union { u32 u[4]; s16x8 v; } bf;
          bf.u[0] = lx[base];
          bf.u[1] = lx[base + 1];
          bf.u[2] = lx[base + 34];
          bf.u[3] = lx[base + 35];
          a1acc = mfma16x16x32(af1, bf.v, a1acc);
        }
        const int rowlocal = ohl + 1 - rh;   // A1H padded-local row
        #pragma unroll
        for (int r = 0; r < 4; ++r) {
          const int co = quad * 4 + r;
          float v = a1acc[r] + consts[h * 16 + co];
          v = v > 0.f ? v : 0.f;
          lp[(3740 + co * 324 + rowlocal * 18) * 2 + ob + l15 + 1] = f2bf(v);
        }
      }
    }
    __syncthreads();  // a1 half ready
    // ---- conv2 K-half: planes 16h..16h+15, local output row wv ----
    #pragma unroll
    for (int kst = 0; kst < 8; ++kst) {
      const int kglob = h * 8 + kst;
      s16x8 afr[4];
      #pragma unroll
      for (int mt = 0; mt < 4; ++mt)
        afr[mt] = *(const s16x8*)(w2c + (mt * 16 + l15) * 512 + kglob * 32 + quad * 8);
      const int ci = kst * 2 + cih;
      const int base = 3740 + ci * 324 + (2 * wv + khb) * 18 + l15;
      union { u32 u[4]; s16x8 v; } bf;
      bf.u[0] = lx[base];
      bf.u[1] = lx[base + 1];
      bf.u[2] = lx[base + 18];
      bf.u[3] = lx[base + 19];
      #pragma unroll
      for (int mt = 0; mt < 4; ++mt)
        acc2[mt] = mfma16x16x32(afr[mt], bf.v, acc2[mt]);
    }
    if (h == 0) __syncthreads();  // conv2 h0 done reading before conv1 h1 writes
  }
  // ---- epilogue: feats ----
  const int oh = wv + 8 * rh;
  #pragma unroll
  for (int mt = 0; mt < 4; ++mt)
    #pragma unroll
    for (int r = 0; r < 4; ++r) {
      const int co = mt * 16 + quad * 4 + r;
      float v = acc2[mt][r] + consts[32 + co];
      v = v > 0.f ? v : 0.f;
      feats[(size_t)n * 16384 + co * 256 + oh * 16 + l15] = f2bf(v);
    }
}

// ---------- xb partials: feats @ bb_w[:16384], split-K=16, M-tile=32 ------
__global__ __launch_bounds__(256)
void k_xb(const u16* __restrict__ feats, const u16* __restrict__ bbT,
          float* __restrict__ xbp) {
  const int m0 = blockIdx.x * 32;
  const int kc = blockIdx.y;
  const int kc0 = kc * 1024;
  const int tid = threadIdx.x;
  const int w = tid >> 6, lane = tid & 63, quad = lane >> 4, l15 = lane & 15;
  f32x4 acc[2][2];
  #pragma unroll
  for (int mt = 0; mt < 2; ++mt)
    #pragma unroll
    for (int i = 0; i < 2; ++i) acc[mt][i] = f32x4{0.f, 0.f, 0.f, 0.f};
  #pragma unroll 4
  for (int kst = 0; kst < 32; ++kst) {
    const int k = kc0 + kst * 32 + quad * 8;
    s16x8 afrag[2], bfrag[2];
    #pragma unroll
    for (int mt = 0; mt < 2; ++mt)
      afrag[mt] = *(const s16x8*)(feats + (size_t)(m0 + mt * 16 + l15) * 16384 + k);
    #pragma unroll
    for (int i = 0; i < 2; ++i)
      bfrag[i] = *(const s16x8*)(bbT + (size_t)((w * 2 + i) * 16 + l15) * 16448 + k);
    #pragma unroll
    for (int mt = 0; mt < 2; ++mt)
      #pragma unroll
      for (int i = 0; i < 2; ++i)
        acc[mt][i] = mfma16x16x32(afrag[mt], bfrag[i], acc[mt][i]);
  }
  float* dst = xbp + (size_t)kc * 262144;
  #pragma unroll
  for (int mt = 0; mt < 2; ++mt)
    #pragma unroll
    for (int i = 0; i < 2; ++i) {
      const int j = (w * 2 + i) * 16 + l15;
      #pragma unroll
      for (int r = 0; r < 4; ++r) {
        const int m = m0 + mt * 16 + quad * 4 + r;
        dst[m * 128 + j] = acc[mt][i][r];
      }
    }
}

// ---------- reduce split-K partials -> xb ----------
__global__ __launch_bounds__(256)
void k_xbsum(const float* __restrict__ xbp, float* __restrict__ xb) {
  const int e = blockIdx.x * 256 + threadIdx.x;
  float s = 0.f;
  #pragma unroll
  for (int kc = 0; kc < 16; ++kc) s += xbp[(size_t)kc * 262144 + e];
  xb[e] = s;
}

// ---------- CfC recurrence: one block per batch row, 3 barriers/step ----------
__global__ __launch_bounds__(256)
void k_rec(const int* __restrict__ flagp, const float* __restrict__ xb,
           const u16* __restrict__ bbT, const u16* __restrict__ HT,
           const float* __restrict__ consts, float* __restrict__ rout,
           void* __restrict__ outv) {
  __shared__ float xbl[64 * 128];
  __shared__ float h[64];
  __shared__ float bbv[128];
  __shared__ float heads[256];
  const int isbf = *flagp;
  const int b = blockIdx.x;
  const int tid = threadIdx.x;
  {
    const float* src = xb + (size_t)b * 64 * 128;
    #pragma unroll
    for (int q = 0; q < 32; ++q) xbl[q * 256 + tid] = src[q * 256 + tid];
  }
  // phase-1 weights: full K=64 column for j = tid (threads 0..127)
  float w1r[64];
  if (tid < 128) {
    const u32* src = (const u32*)(bbT + (size_t)tid * 16448 + 16384);
    #pragma unroll
    for (int q = 0; q < 32; ++q) bf2x2(src[q], w1r[2 * q], w1r[2 * q + 1]);
  }
  float w2r[128];
  {
    const u32* src = (const u32*)(HT + tid * 128);
    #pragma unroll
    for (int q = 0; q < 64; ++q) bf2x2(src[q], w2r[2 * q], w2r[2 * q + 1]);
  }
  const float hbias = consts[224 + tid];
  const float bbias = (tid < 128) ? consts[96 + tid] : 0.f;
  if (tid < 64) h[tid] = consts[1000 + b * 64 + tid];
  __syncthreads();
  for (int t = 0; t < 64; ++t) {
    if (tid < 128) {
      float p0 = 0.f, p1 = 0.f, p2 = 0.f, p3 = 0.f;
      #pragma unroll
      for (int q = 0; q < 16; ++q) {
        p0 += h[4 * q + 0] * w1r[4 * q + 0];
        p1 += h[4 * q + 1] * w1r[4 * q + 1];
        p2 += h[4 * q + 2] * w1r[4 * q + 2];
        p3 += h[4 * q + 3] * w1r[4 * q + 3];
      }
      const float s = (p0 + p1) + (p2 + p3) + xbl[t * 128 + tid] + bbias;
      bbv[tid] = 1.7159f * fast_tanh(0.666f * s);
    }
    __syncthreads();
    float c0 = 0.f, c1 = 0.f, c2 = 0.f, c3 = 0.f;
    #pragma unroll
    for (int q = 0; q < 32; ++q) {
      c0 += bbv[4 * q + 0] * w2r[4 * q + 0];
      c1 += bbv[4 * q + 1] * w2r[4 * q + 1];
      c2 += bbv[4 * q + 2] * w2r[4 * q + 2];
      c3 += bbv[4 * q + 3] * w2r[4 * q + 3];
    }
    heads[tid] = (c0 + c1) + (c2 + c3) + hbias;
    __syncthreads();
    if (tid < 64) {
      const float ff1 = fast_tanh(heads[tid]);
      const float ff2 = fast_tanh(heads[64 + tid]);
      const float ti = 1.f / (1.f + __expf(-(heads[128 + tid] + heads[192 + tid])));
      const float hn = ff1 * (1.f - ti) + ti * ff2;
      h[tid] = hn;
      rout[((size_t)b * 64 + t) * 64 + tid] = hn;
    }
    __syncthreads();
  }
  if (tid < 64) {
    if (isbf) ((u16*)outv)[16384 + b * 64 + tid] = f2bf(h[tid]);
    else      ((float*)outv)[16384 + b * 64 + tid] = h[tid];
  }
}

// ---------- logits = rout @ out_w + out_b ----------
__global__ __launch_bounds__(256)
void k_logits(const int* __restrict__ flagp, const float* __restrict__ rout,
              const float* __restrict__ consts, void* __restrict__ outv) {
  __shared__ float W[512];
  __shared__ float Bv[8];
  const int isbf = *flagp;
  const int tid = threadIdx.x;
  for (int e = tid; e < 512; e += 256) W[e] = consts[480 + e];
  if (tid < 8) Bv[tid] = consts[992 + tid];
  __syncthreads();
  const int bt = blockIdx.x * 256 + tid;
  float acc[8];
  #pragma unroll
  for (int c = 0; c < 8; ++c) acc[c] = Bv[c];
  const f32x4* r = (const f32x4*)(rout + (size_t)bt * 64);
  #pragma unroll
  for (int q = 0; q < 16; ++q) {
    f32x4 v = r[q];
    #pragma unroll
    for (int u = 0; u < 4; ++u) {
      const float rv = v[u];
      const int i = 4 * q + u;
      #pragma unroll
      for (int c = 0; c < 8; ++c) acc[c] += rv * W[i * 8 + c];
    }
  }
  if (isbf) {
    u32 pk[4];
    #pragma unroll
    for (int c = 0; c < 4; ++c)
      pk[c] = (u32)f2bf(acc[2 * c]) | ((u32)f2bf(acc[2 * c + 1]) << 16);
    *(uint4*)((u16*)outv + (size_t)bt * 8) = *(const uint4*)pk;
  } else {
    float* o = (float*)outv + (size_t)bt * 8;
    *(f32x4*)o = f32x4{acc[0], acc[1], acc[2], acc[3]};
    *(f32x4*)(o + 4) = f32x4{acc[4], acc[5], acc[6], acc[7]};
  }
}

extern "C" void kernel_launch(void* const* d_in, const int* in_sizes, int n_in,
                              void* d_out, int out_size, void* d_ws, size_t ws_size,
                              hipStream_t stream) {
  const void* x   = d_in[0];
  const void* hx  = d_in[1];
  const void* w1  = d_in[2];
  const void* b1  = d_in[3];
  const void* w2  = d_in[4];
  const void* b2  = d_in[5];
  const void* bbw = d_in[6];
  const void* bbb = d_in[7];
  const void* f1w = d_in[8];
  const void* f1b = d_in[9];
  const void* f2w = d_in[10];
  const void* f2b = d_in[11];
  const void* taw = d_in[12];
  const void* tab = d_in[13];
  const void* tbw = d_in[14];
  const void* tbb = d_in[15];
  const void* oww = d_in[16];
  const void* obb = d_in[17];

  char* ws = (char*)d_ws;
  float* xbp   = (float*)(ws);
  u16*   feats = (u16*)(ws + 150994944);
  u16*   bbT   = (u16*)(ws + 218103808);
  u16*   HT    = (u16*)(ws + 222314496);
  u16*   w1p   = (u16*)(ws + 222380032);
  u16*   w2c   = (u16*)(ws + 222384128);
  float* xb    = (float*)(ws + 222449664);
  float* rout  = (float*)(ws + 223498240);
  float* consts= (float*)(ws + 224022528);
  int*   flag  = (int*)(ws + 224034816);

  k_prep_all<<<670, 256, 0, stream>>>((const u32*)bbw, b1, b2, bbb, f1b, f2b,
                                      tab, tbb, oww, obb, hx, w1, w2, bbw,
                                      f1w, f2w, taw, tbw,
                                      consts, w1p, w2c, bbT, HT, flag);
  k_convs<<<4096, 512, 0, stream>>>(flag, x, w1p, w2c, consts, feats);
  k_xb<<<dim3(64, 16), 256, 0, stream>>>(feats, bbT, xbp);
  k_xbsum<<<1024, 256, 0, stream>>>(xbp, xb);
  k_rec<<<32, 256, 0, stream>>>(flag, xb, bbT, HT, consts, rout, d_out);
  k_logits<<<8, 256, 0, stream>>>(flag, rout, consts, d_out);
}

// Round 7
// 590.799 us; speedup vs baseline: 1.0230x; 1.0227x over previous
//
#include <hip/hip_runtime.h>
#include <stdint.h>

// DoomLiquidNet: conv(3->32,k4s2p1) -> conv(32->64,k4s2p1) -> CfC core -> logits
// Inputs f32 (detected on device; bf16 fallback kept). Compute in bf16 MFMA.
//
// R13 = R12 resubmit (R12 bench was an infra failure: container died twice,
//   no counters; kernel re-audited for OOB/hangs - clean. Same pattern as
//   R8->R9 which cleared on identical resubmit).
// R12: k_convs = half-image blocks (R7 geometry, correctness-proven) with
//   FULL 32-plane A1 in LDS -> serial chain stage|bar|conv1|bar|conv2
//   (2 barriers vs R0's 4, no h ping-pong). LDS 56.4KB -> 2 blocks/CU.
//   launch_bounds(512,4): the ONLY no-spill 512-thr point (empirical law
//   R0..R11: alloc cap = 256/N for 512-thr blocks; N=4 -> 64 = demand).
//   Occupancy theory DEAD: dur uncorrelated with occ across 45..88%
//   (R6 193us@45%, R9 294@44%, R11 298@65%, R7 316@88%); nothing saturated
//   (MFMA 6-9%, VALU 15-21%, HBM 6-9%) -> bound by per-block serial phases.
//   k_xb = R0 version (M-tile 64, grid (32,16)).
//
// ws layout:
//   xbp   : f32  [16][2048][128]     @ 0           16777216 B
//   feats : bf16 [2048][16384]       @ 150994944   67108864 B
//   bbT   : bf16 [128][16448]        @ 218103808    4210688 B
//   HT    : bf16 [256][128]          @ 222314496      65536 B
//   w1p   : bf16 [32][64]            @ 222380032       4096 B
//   w2c   : bf16 [64][512]           @ 222384128      65536 B
//   xb    : f32  [2048][128]         @ 222449664    1048576 B
//   rout  : f32  [2048][64]          @ 223498240     524288 B
//   consts: f32  [3048]              @ 224022528      12288 B
//   flag  : int                      @ 224034816          4 B

typedef unsigned short u16;
typedef unsigned int u32;

typedef float f32x4 __attribute__((ext_vector_type(4)));
typedef short s16x8 __attribute__((ext_vector_type(8)));
typedef __bf16 b16x8 __attribute__((ext_vector_type(8)));

template <typename V>
__device__ inline auto mfma_sel(V a, V b, f32x4 c, int)
    -> decltype(__builtin_amdgcn_mfma_f32_16x16x32_bf16(a, b, c, 0, 0, 0)) {
  return __builtin_amdgcn_mfma_f32_16x16x32_bf16(a, b, c, 0, 0, 0);
}
template <typename V>
__device__ inline f32x4 mfma_sel(V a, V b, f32x4 c, long) {
  union UU { V s; b16x8 b; };
  UU ua; ua.s = a;
  UU ub; ub.s = b;
  return __builtin_amdgcn_mfma_f32_16x16x32_bf16(ua.b, ub.b, c, 0, 0, 0);
}
__device__ inline f32x4 mfma16x16x32(s16x8 a, s16x8 b, f32x4 c) {
  return mfma_sel(a, b, c, 0);
}

__device__ inline float bf2f(u16 v) {
  union { u32 i; float f; } x; x.i = ((u32)v) << 16; return x.f;
}
__device__ inline u16 f2bf(float f) {  // round-to-nearest-even
  union { float f; u32 i; } x; x.f = f;
  u32 i = x.i;
  i += 0x7fffu + ((i >> 16) & 1u);
  return (u16)(i >> 16);
}
__device__ inline void bf2x2(u32 u, float& lo, float& hi) {
  union { u32 i; float f; } a, b;
  a.i = u << 16; b.i = u & 0xffff0000u;
  lo = a.f; hi = b.f;
}
__device__ inline float ldf(int isbf, const void* p, size_t i) {
  return isbf ? bf2f(((const u16*)p)[i]) : ((const float*)p)[i];
}
__device__ inline u16 ldb(int isbf, const void* p, size_t i) {
  return isbf ? ((const u16*)p)[i] : f2bf(((const float*)p)[i]);
}
__device__ inline float fast_tanh(float x) {
  float ax = fabsf(x);
  float e = __expf(2.0f * ax);
  float t = 1.0f - 2.0f / (e + 1.0f);
  return copysignf(t, x);
}

// ---------- fused prep: detect + consts + w1p + w2c + bbT + HT ----------
__global__ __launch_bounds__(256)
void k_prep_all(const u32* __restrict__ bwords,
                const void* b1, const void* b2, const void* bbb,
                const void* f1b, const void* f2b, const void* tab,
                const void* tbb, const void* oww, const void* obb,
                const void* hx, const void* w1, const void* w2,
                const void* bw, const void* f1w, const void* f2w,
                const void* taw, const void* tbw,
                float* __restrict__ consts, u16* __restrict__ w1p,
                u16* __restrict__ w2c, u16* __restrict__ bbT,
                u16* __restrict__ HT, int* __restrict__ flag) {
  __shared__ u16 t[64][65];
  const int tid = threadIdx.x;
  const int b = blockIdx.x;
  const u32 wd = bwords[tid & 63];
  const u32 ex = (wd >> 7) & 0xFFu;
  unsigned long long m = __ballot(ex >= 100u && ex <= 126u);
  const int isbf = (__popcll(m) >= 32) ? 1 : 0;
  if (b == 0 && tid == 0) *flag = isbf;

  if (b < 12) {
    const int e = b * 256 + tid;
    if (e >= 3048) return;
    float v;
    if (e < 32)        v = ldf(isbf, b1, e);
    else if (e < 96)   v = ldf(isbf, b2, e - 32);
    else if (e < 224)  v = ldf(isbf, bbb, e - 96);
    else if (e < 288)  v = ldf(isbf, f1b, e - 224);
    else if (e < 352)  v = ldf(isbf, f2b, e - 288);
    else if (e < 416)  v = ldf(isbf, tab, e - 352);
    else if (e < 480)  v = ldf(isbf, tbb, e - 416);
    else if (e < 992)  v = ldf(isbf, oww, e - 480);
    else if (e < 1000) v = ldf(isbf, obb, e - 992);
    else               v = ldf(isbf, hx, e - 1000);
    consts[e] = v;
  } else if (b < 20) {
    const int e = (b - 12) * 256 + tid;
    const int k = e & 63, co = e >> 6;
    w1p[e] = (k < 48) ? ldb(isbf, w1, co * 48 + k) : (u16)0;
  } else if (b < 148) {
    const int e = (b - 20) * 256 + tid;
    w2c[e] = ldb(isbf, w2, e);
  } else if (b < 662) {
    const int idx = b - 148;
    const int k0 = (idx >> 1) * 64, j0 = (idx & 1) * 64;
    #pragma unroll
    for (int i = 0; i < 16; ++i) {
      int e = tid + 256 * i;
      int kl = e >> 6, jl = e & 63;
      t[kl][jl] = ldb(isbf, bw, (size_t)(k0 + kl) * 128 + j0 + jl);
    }
    __syncthreads();
    #pragma unroll
    for (int i = 0; i < 16; ++i) {
      int e = tid + 256 * i;
      int jl = e >> 6, kl = e & 63;
      bbT[(size_t)(j0 + jl) * 16448 + k0 + kl] = t[kl][jl];
    }
  } else {
    const int idx = b - 662;
    const int h = idx >> 1, i0 = (idx & 1) * 64;
    const void* W = (h == 0) ? f1w : (h == 1) ? f2w : (h == 2) ? taw : tbw;
    #pragma unroll
    for (int i = 0; i < 16; ++i) {
      int e = tid + 256 * i;
      int il = e >> 6, cl = e & 63;
      t[il][cl] = ldb(isbf, W, (i0 + il) * 64 + cl);
    }
    __syncthreads();
    #pragma unroll
    for (int i = 0; i < 16; ++i) {
      int e = tid + 256 * i;
      int cl = e >> 6, il = e & 63;
      HT[(h * 64 + cl) * 128 + i0 + il] = t[il][cl];
    }
  }
}

// ---------- fused conv1+conv2, HALF-IMAGE blocks, FULL A1, 2 barriers ----
// block = (n = bx>>1, rh = bx&1); rh selects conv2 output rows [8rh, 8rh+8).
// LDS u32 map:
//   XS   @ 0    : 3 planes x 36 rows x 34 u32 (shifted-pair; rh=0: x rows
//                 0..34 -> local 1..35, row 0 zero; rh=1: x rows 29..63 ->
//                 local 0..34, row 35 zero)                         3672
//   ZS   @ 3672 : 68 u32 zeros (conv1 K-pad plane reads)              68
//   A1F  @ 3740 : 32 planes x 18 rows x 18 u32 (local row = a1row+1-16rh)
//                                                                  10368
//   total 14108 u32 = 56432 B -> 2 blocks/CU
__global__ __launch_bounds__(512, 4)
void k_convs(const int* __restrict__ flagp, const void* __restrict__ x,
             const u16* __restrict__ w1p, const u16* __restrict__ w2c,
             const float* __restrict__ consts, u16* __restrict__ feats) {
  __shared__ u32 lx[14108];
  const int isbf = *flagp;
  const int n = blockIdx.x >> 1;
  const int rh = blockIdx.x & 1;
  const int tid = threadIdx.x;
  const int wv = tid >> 6, lane = tid & 63, quad = lane >> 4, l15 = lane & 15;

  // zero: XS border row (102) + zero strip (68) + whole A1F (10368)
  const int brow = rh ? 35 : 0;
  for (int e = tid; e < 10538; e += 512) {
    int idx;
    if (e < 102) {
      const int pl = e / 34;
      idx = pl * 1224 + brow * 34 + (e - pl * 34);
    } else if (e < 170) {
      idx = 3672 + (e - 102);
    } else {
      idx = 3740 + (e - 170);
    }
    lx[idx] = 0u;
  }
  // stage x rows [29*rh, 29*rh+34] -> XS local rows rl+1-rh, shifted-pair bf16
  for (int e = tid; e < 1680; e += 512) {
    const int rt = e >> 4;        // 0..104 = (ci, rl)
    const int tt = e & 15;
    const int ci = rt / 35;
    const int rl = rt - ci * 35;  // 0..34
    const int rr = rl + 29 * rh;  // source x row
    u32* dst = &lx[(ci * 36 + rl + 1 - rh) * 34];
    if (!isbf) {
      const float* src = (const float*)x + (((size_t)n * 3 + ci) * 64 + rr) * 64 + 4 * tt;
      const f32x4 v = *(const f32x4*)src;
      const float pv = tt ? src[-1] : 0.f;
      dst[2 * tt]     = (u32)f2bf(pv)   | (((u32)f2bf(v[0])) << 16);
      dst[2 * tt + 1] = (u32)f2bf(v[1]) | (((u32)f2bf(v[2])) << 16);
      if (tt == 15) { dst[32] = (u32)f2bf(v[3]); dst[33] = 0u; }
    } else {
      const u16* src = (const u16*)x + (((size_t)n * 3 + ci) * 64 + rr) * 64 + 4 * tt;
      const u16 pv = tt ? src[-1] : (u16)0;
      dst[2 * tt]     = (u32)pv | (((u32)src[0]) << 16);
      dst[2 * tt + 1] = (u32)src[1] | (((u32)src[2]) << 16);
      if (tt == 15) { dst[32] = (u32)src[3]; dst[33] = 0u; }
    }
  }
  __syncthreads();  // barrier 1: x staged

  const int khb = (quad & 1) * 2;
  const int cih = quad >> 1;
  u16* lp = (u16*)lx;

  // ---- conv1: ALL 32 planes (a1 rows [15*rh, 15*rh+16]) -> A1F ----
  #pragma unroll
  for (int h = 0; h < 2; ++h) {
    const s16x8 af0 = *(const s16x8*)(w1p + (h * 16 + l15) * 64 + quad * 8);
    const s16x8 af1 = *(const s16x8*)(w1p + (h * 16 + l15) * 64 + 32 + quad * 8);
    #pragma unroll
    for (int i = 0; i < 5; ++i) {
      const int nt = wv + 8 * i;   // 34 tiles = 17 rows x 2 col-blocks
      if (nt < 34) {
        const int ohl = nt >> 1;         // local a1 row 0..16
        const int ob = (nt & 1) * 16;
        const int r1 = 2 * ohl + khb;    // local padded-x row
        f32x4 a1acc = f32x4{0.f, 0.f, 0.f, 0.f};
        {
          const int base = (cih * 36 + r1) * 34 + ob + l15;
          union { u32 u[4]; s16x8 v; } bf;
          bf.u[0] = lx[base];
          bf.u[1] = lx[base + 1];
          bf.u[2] = lx[base + 34];
          bf.u[3] = lx[base + 35];
          a1acc = mfma16x16x32(af0, bf.v, a1acc);
        }
        {
          // ci1 = 2+cih: plane 2 real, plane 3 = K-pad -> zero strip
          const int base = (cih == 0) ? ((2 * 36 + r1) * 34 + ob + l15)
                                      : (3672 + ob + l15);
          union { u32 u[4]; s16x8 v; } bf;
          bf.u[0] = lx[base];
          bf.u[1] = lx[base + 1];
          bf.u[2] = lx[base + 34];
          bf.u[3] = lx[base + 35];
          a1acc = mfma16x16x32(af1, bf.v, a1acc);
        }
        const int rowlocal = ohl + 1 - rh;   // A1F padded-local row
        #pragma unroll
        for (int r = 0; r < 4; ++r) {
          const int co = h * 16 + quad * 4 + r;
          float v = a1acc[r] + consts[co];
          v = v > 0.f ? v : 0.f;
          lp[(3740 + co * 324 + rowlocal * 18) * 2 + ob + l15 + 1] = f2bf(v);
        }
      }
    }
  }
  __syncthreads();  // barrier 2: a1 complete

  // ---- conv2: all 16 K-steps, uninterrupted ----
  f32x4 acc2[4];
  #pragma unroll
  for (int mt = 0; mt < 4; ++mt) acc2[mt] = f32x4{0.f, 0.f, 0.f, 0.f};
  #pragma unroll
  for (int kst = 0; kst < 16; ++kst) {
    s16x8 afr[4];
    #pragma unroll
    for (int mt = 0; mt < 4; ++mt)
      afr[mt] = *(const s16x8*)(w2c + (mt * 16 + l15) * 512 + kst * 32 + quad * 8);
    const int ci = kst * 2 + cih;
    const int base = 3740 + ci * 324 + (2 * wv + khb) * 18 + l15;
    union { u32 u[4]; s16x8 v; } bf;
    bf.u[0] = lx[base];
    bf.u[1] = lx[base + 1];
    bf.u[2] = lx[base + 18];
    bf.u[3] = lx[base + 19];
    #pragma unroll
    for (int mt = 0; mt < 4; ++mt)
      acc2[mt] = mfma16x16x32(afr[mt], bf.v, acc2[mt]);
  }
  // ---- epilogue: feats ----
  const int oh = wv + 8 * rh;
  #pragma unroll
  for (int mt = 0; mt < 4; ++mt)
    #pragma unroll
    for (int r = 0; r < 4; ++r) {
      const int co = mt * 16 + quad * 4 + r;
      float v = acc2[mt][r] + consts[32 + co];
      v = v > 0.f ? v : 0.f;
      feats[(size_t)n * 16384 + co * 256 + oh * 16 + l15] = f2bf(v);
    }
}

// ---------- xb partials: feats @ bb_w[:16384], split-K=16, NO atomics ------
__global__ __launch_bounds__(256)
void k_xb(const u16* __restrict__ feats, const u16* __restrict__ bbT,
          float* __restrict__ xbp) {
  const int m0 = blockIdx.x * 64;
  const int kc = blockIdx.y;
  const int kc0 = kc * 1024;
  const int tid = threadIdx.x;
  const int w = tid >> 6, lane = tid & 63, quad = lane >> 4, l15 = lane & 15;
  f32x4 acc[4][2];
  #pragma unroll
  for (int mt = 0; mt < 4; ++mt)
    #pragma unroll
    for (int i = 0; i < 2; ++i) acc[mt][i] = f32x4{0.f, 0.f, 0.f, 0.f};
  #pragma unroll 4
  for (int kst = 0; kst < 32; ++kst) {
    const int k = kc0 + kst * 32 + quad * 8;
    s16x8 afrag[4], bfrag[2];
    #pragma unroll
    for (int mt = 0; mt < 4; ++mt)
      afrag[mt] = *(const s16x8*)(feats + (size_t)(m0 + mt * 16 + l15) * 16384 + k);
    #pragma unroll
    for (int i = 0; i < 2; ++i)
      bfrag[i] = *(const s16x8*)(bbT + (size_t)((w * 2 + i) * 16 + l15) * 16448 + k);
    #pragma unroll
    for (int mt = 0; mt < 4; ++mt)
      #pragma unroll
      for (int i = 0; i < 2; ++i)
        acc[mt][i] = mfma16x16x32(afrag[mt], bfrag[i], acc[mt][i]);
  }
  float* dst = xbp + (size_t)kc * 262144;
  #pragma unroll
  for (int mt = 0; mt < 4; ++mt)
    #pragma unroll
    for (int i = 0; i < 2; ++i) {
      const int j = (w * 2 + i) * 16 + l15;
      #pragma unroll
      for (int r = 0; r < 4; ++r) {
        const int m = m0 + mt * 16 + quad * 4 + r;
        dst[m * 128 + j] = acc[mt][i][r];
      }
    }
}

// ---------- reduce split-K partials -> xb ----------
__global__ __launch_bounds__(256)
void k_xbsum(const float* __restrict__ xbp, float* __restrict__ xb) {
  const int e = blockIdx.x * 256 + threadIdx.x;
  float s = 0.f;
  #pragma unroll
  for (int kc = 0; kc < 16; ++kc) s += xbp[(size_t)kc * 262144 + e];
  xb[e] = s;
}

// ---------- CfC recurrence: one block per batch row, 3 barriers/step ----------
__global__ __launch_bounds__(256)
void k_rec(const int* __restrict__ flagp, const float* __restrict__ xb,
           const u16* __restrict__ bbT, const u16* __restrict__ HT,
           const float* __restrict__ consts, float* __restrict__ rout,
           void* __restrict__ outv) {
  __shared__ float xbl[64 * 128];
  __shared__ float h[64];
  __shared__ float bbv[128];
  __shared__ float heads[256];
  const int isbf = *flagp;
  const int b = blockIdx.x;
  const int tid = threadIdx.x;
  {
    const float* src = xb + (size_t)b * 64 * 128;
    #pragma unroll
    for (int q = 0; q < 32; ++q) xbl[q * 256 + tid] = src[q * 256 + tid];
  }
  // phase-1 weights: full K=64 column for j = tid (threads 0..127)
  float w1r[64];
  if (tid < 128) {
    const u32* src = (const u32*)(bbT + (size_t)tid * 16448 + 16384);
    #pragma unroll
    for (int q = 0; q < 32; ++q) bf2x2(src[q], w1r[2 * q], w1r[2 * q + 1]);
  }
  float w2r[128];
  {
    const u32* src = (const u32*)(HT + tid * 128);
    #pragma unroll
    for (int q = 0; q < 64; ++q) bf2x2(src[q], w2r[2 * q], w2r[2 * q + 1]);
  }
  const float hbias = consts[224 + tid];
  const float bbias = (tid < 128) ? consts[96 + tid] : 0.f;
  if (tid < 64) h[tid] = consts[1000 + b * 64 + tid];
  __syncthreads();
  for (int t = 0; t < 64; ++t) {
    if (tid < 128) {
      float p0 = 0.f, p1 = 0.f, p2 = 0.f, p3 = 0.f;
      #pragma unroll
      for (int q = 0; q < 16; ++q) {
        p0 += h[4 * q + 0] * w1r[4 * q + 0];
        p1 += h[4 * q + 1] * w1r[4 * q + 1];
        p2 += h[4 * q + 2] * w1r[4 * q + 2];
        p3 += h[4 * q + 3] * w1r[4 * q + 3];
      }
      const float s = (p0 + p1) + (p2 + p3) + xbl[t * 128 + tid] + bbias;
      bbv[tid] = 1.7159f * fast_tanh(0.666f * s);
    }
    __syncthreads();
    float c0 = 0.f, c1 = 0.f, c2 = 0.f, c3 = 0.f;
    #pragma unroll
    for (int q = 0; q < 32; ++q) {
      c0 += bbv[4 * q + 0] * w2r[4 * q + 0];
      c1 += bbv[4 * q + 1] * w2r[4 * q + 1];
      c2 += bbv[4 * q + 2] * w2r[4 * q + 2];
      c3 += bbv[4 * q + 3] * w2r[4 * q + 3];
    }
    heads[tid] = (c0 + c1) + (c2 + c3) + hbias;
    __syncthreads();
    if (tid < 64) {
      const float ff1 = fast_tanh(heads[tid]);
      const float ff2 = fast_tanh(heads[64 + tid]);
      const float ti = 1.f / (1.f + __expf(-(heads[128 + tid] + heads[192 + tid])));
      const float hn = ff1 * (1.f - ti) + ti * ff2;
      h[tid] = hn;
      rout[((size_t)b * 64 + t) * 64 + tid] = hn;
    }
    __syncthreads();
  }
  if (tid < 64) {
    if (isbf) ((u16*)outv)[16384 + b * 64 + tid] = f2bf(h[tid]);
    else      ((float*)outv)[16384 + b * 64 + tid] = h[tid];
  }
}

// ---------- logits = rout @ out_w + out_b ----------
__global__ __launch_bounds__(256)
void k_logits(const int* __restrict__ flagp, const float* __restrict__ rout,
              const float* __restrict__ consts, void* __restrict__ outv) {
  __shared__ float W[512];
  __shared__ float Bv[8];
  const int isbf = *flagp;
  const int tid = threadIdx.x;
  for (int e = tid; e < 512; e += 256) W[e] = consts[480 + e];
  if (tid < 8) Bv[tid] = consts[992 + tid];
  __syncthreads();
  const int bt = blockIdx.x * 256 + tid;
  float acc[8];
  #pragma unroll
  for (int c = 0; c < 8; ++c) acc[c] = Bv[c];
  const f32x4* r = (const f32x4*)(rout + (size_t)bt * 64);
  #pragma unroll
  for (int q = 0; q < 16; ++q) {
    f32x4 v = r[q];
    #pragma unroll
    for (int u = 0; u < 4; ++u) {
      const float rv = v[u];
      const int i = 4 * q + u;
      #pragma unroll
      for (int c = 0; c < 8; ++c) acc[c] += rv * W[i * 8 + c];
    }
  }
  if (isbf) {
    u32 pk[4];
    #pragma unroll
    for (int c = 0; c < 4; ++c)
      pk[c] = (u32)f2bf(acc[2 * c]) | ((u32)f2bf(acc[2 * c + 1]) << 16);
    *(uint4*)((u16*)outv + (size_t)bt * 8) = *(const uint4*)pk;
  } else {
    float* o = (float*)outv + (size_t)bt * 8;
    *(f32x4*)o = f32x4{acc[0], acc[1], acc[2], acc[3]};
    *(f32x4*)(o + 4) = f32x4{acc[4], acc[5], acc[6], acc[7]};
  }
}

extern "C" void kernel_launch(void* const* d_in, const int* in_sizes, int n_in,
                              void* d_out, int out_size, void* d_ws, size_t ws_size,
                              hipStream_t stream) {
  const void* x   = d_in[0];
  const void* hx  = d_in[1];
  const void* w1  = d_in[2];
  const void* b1  = d_in[3];
  const void* w2  = d_in[4];
  const void* b2  = d_in[5];
  const void* bbw = d_in[6];
  const void* bbb = d_in[7];
  const void* f1w = d_in[8];
  const void* f1b = d_in[9];
  const void* f2w = d_in[10];
  const void* f2b = d_in[11];
  const void* taw = d_in[12];
  const void* tab = d_in[13];
  const void* tbw = d_in[14];
  const void* tbb = d_in[15];
  const void* oww = d_in[16];
  const void* obb = d_in[17];

  char* ws = (char*)d_ws;
  float* xbp   = (float*)(ws);
  u16*   feats = (u16*)(ws + 150994944);
  u16*   bbT   = (u16*)(ws + 218103808);
  u16*   HT    = (u16*)(ws + 222314496);
  u16*   w1p   = (u16*)(ws + 222380032);
  u16*   w2c   = (u16*)(ws + 222384128);
  float* xb    = (float*)(ws + 222449664);
  float* rout  = (float*)(ws + 223498240);
  float* consts= (float*)(ws + 224022528);
  int*   flag  = (int*)(ws + 224034816);

  k_prep_all<<<670, 256, 0, stream>>>((const u32*)bbw, b1, b2, bbb, f1b, f2b,
                                      tab, tbb, oww, obb, hx, w1, w2, bbw,
                                      f1w, f2w, taw, tbw,
                                      consts, w1p, w2c, bbT, HT, flag);
  k_convs<<<4096, 512, 0, stream>>>(flag, x, w1p, w2c, consts, feats);
  k_xb<<<dim3(32, 16), 256, 0, stream>>>(feats, bbT, xbp);
  k_xbsum<<<1024, 256, 0, stream>>>(xbp, xb);
  k_rec<<<32, 256, 0, stream>>>(flag, xb, bbT, HT, consts, rout, d_out);
  k_logits<<<8, 256, 0, stream>>>(flag, rout, consts, d_out);
}

// Round 8
// 421.033 us; speedup vs baseline: 1.4354x; 1.4032x over previous
//
#include <hip/hip_runtime.h>
#include <stdint.h>

// DoomLiquidNet: conv(3->32,k4s2p1) -> conv(32->64,k4s2p1) -> CfC core -> logits
// Inputs f32 (detected on device; bf16 fallback kept). Compute in bf16 MFMA.
//
// R14: exact R0 k_convs (proven 193us) + conv2 wave remap (mt,og):
//   wave wv -> mt = wv&3 (co-group), og = wv>>2 (oh-octet).
//   Per kst: ONE w2c fragment load (was 4) x 8 MFMA vs 8 a1 LDS fragments.
//   Per-wave w2c traffic 64KB -> 16KB. Evidence: R6 vs R13 per-block-round
//   fit gives fixed cost F~26us/round independent of rows computed; the only
//   row-invariant per-wave cost is conv2 reading ALL of w2c (4mt x 16kst).
//   All grid-split rounds (R7/R9/R11/R13) doubled this invariant -> ~300us.
//   Everything else byte-identical to R0 (5-phase ping-pong, 66.4KB LDS,
//   grid 2048x512, launch_bounds(512,4) = the proven no-spill point).
//
// ws layout:
//   xbp   : f32  [16][2048][128]     @ 0           16777216 B
//   feats : bf16 [2048][16384]       @ 150994944   67108864 B
//   bbT   : bf16 [128][16448]        @ 218103808    4210688 B
//   HT    : bf16 [256][128]          @ 222314496      65536 B
//   w1p   : bf16 [32][64]            @ 222380032       4096 B
//   w2c   : bf16 [64][512]           @ 222384128      65536 B
//   xb    : f32  [2048][128]         @ 222449664    1048576 B
//   rout  : f32  [2048][64]          @ 223498240     524288 B
//   consts: f32  [3048]              @ 224022528      12288 B
//   flag  : int                      @ 224034816          4 B

typedef unsigned short u16;
typedef unsigned int u32;

typedef float f32x4 __attribute__((ext_vector_type(4)));
typedef short s16x8 __attribute__((ext_vector_type(8)));
typedef __bf16 b16x8 __attribute__((ext_vector_type(8)));

template <typename V>
__device__ inline auto mfma_sel(V a, V b, f32x4 c, int)
    -> decltype(__builtin_amdgcn_mfma_f32_16x16x32_bf16(a, b, c, 0, 0, 0)) {
  return __builtin_amdgcn_mfma_f32_16x16x32_bf16(a, b, c, 0, 0, 0);
}
template <typename V>
__device__ inline f32x4 mfma_sel(V a, V b, f32x4 c, long) {
  union UU { V s; b16x8 b; };
  UU ua; ua.s = a;
  UU ub; ub.s = b;
  return __builtin_amdgcn_mfma_f32_16x16x32_bf16(ua.b, ub.b, c, 0, 0, 0);
}
__device__ inline f32x4 mfma16x16x32(s16x8 a, s16x8 b, f32x4 c) {
  return mfma_sel(a, b, c, 0);
}

__device__ inline float bf2f(u16 v) {
  union { u32 i; float f; } x; x.i = ((u32)v) << 16; return x.f;
}
__device__ inline u16 f2bf(float f) {  // round-to-nearest-even
  union { float f; u32 i; } x; x.f = f;
  u32 i = x.i;
  i += 0x7fffu + ((i >> 16) & 1u);
  return (u16)(i >> 16);
}
__device__ inline void bf2x2(u32 u, float& lo, float& hi) {
  union { u32 i; float f; } a, b;
  a.i = u << 16; b.i = u & 0xffff0000u;
  lo = a.f; hi = b.f;
}
__device__ inline float ldf(int isbf, const void* p, size_t i) {
  return isbf ? bf2f(((const u16*)p)[i]) : ((const float*)p)[i];
}
__device__ inline u16 ldb(int isbf, const void* p, size_t i) {
  return isbf ? ((const u16*)p)[i] : f2bf(((const float*)p)[i]);
}
__device__ inline float fast_tanh(float x) {
  float ax = fabsf(x);
  float e = __expf(2.0f * ax);
  float t = 1.0f - 2.0f / (e + 1.0f);
  return copysignf(t, x);
}

// ---------- fused prep: detect + consts + w1p + w2c + bbT + HT ----------
__global__ __launch_bounds__(256)
void k_prep_all(const u32* __restrict__ bwords,
                const void* b1, const void* b2, const void* bbb,
                const void* f1b, const void* f2b, const void* tab,
                const void* tbb, const void* oww, const void* obb,
                const void* hx, const void* w1, const void* w2,
                const void* bw, const void* f1w, const void* f2w,
                const void* taw, const void* tbw,
                float* __restrict__ consts, u16* __restrict__ w1p,
                u16* __restrict__ w2c, u16* __restrict__ bbT,
                u16* __restrict__ HT, int* __restrict__ flag) {
  __shared__ u16 t[64][65];
  const int tid = threadIdx.x;
  const int b = blockIdx.x;
  const u32 wd = bwords[tid & 63];
  const u32 ex = (wd >> 7) & 0xFFu;
  unsigned long long m = __ballot(ex >= 100u && ex <= 126u);
  const int isbf = (__popcll(m) >= 32) ? 1 : 0;
  if (b == 0 && tid == 0) *flag = isbf;

  if (b < 12) {
    const int e = b * 256 + tid;
    if (e >= 3048) return;
    float v;
    if (e < 32)        v = ldf(isbf, b1, e);
    else if (e < 96)   v = ldf(isbf, b2, e - 32);
    else if (e < 224)  v = ldf(isbf, bbb, e - 96);
    else if (e < 288)  v = ldf(isbf, f1b, e - 224);
    else if (e < 352)  v = ldf(isbf, f2b, e - 288);
    else if (e < 416)  v = ldf(isbf, tab, e - 352);
    else if (e < 480)  v = ldf(isbf, tbb, e - 416);
    else if (e < 992)  v = ldf(isbf, oww, e - 480);
    else if (e < 1000) v = ldf(isbf, obb, e - 992);
    else               v = ldf(isbf, hx, e - 1000);
    consts[e] = v;
  } else if (b < 20) {
    const int e = (b - 12) * 256 + tid;
    const int k = e & 63, co = e >> 6;
    w1p[e] = (k < 48) ? ldb(isbf, w1, co * 48 + k) : (u16)0;
  } else if (b < 148) {
    const int e = (b - 20) * 256 + tid;
    w2c[e] = ldb(isbf, w2, e);
  } else if (b < 662) {
    const int idx = b - 148;
    const int k0 = (idx >> 1) * 64, j0 = (idx & 1) * 64;
    #pragma unroll
    for (int i = 0; i < 16; ++i) {
      int e = tid + 256 * i;
      int kl = e >> 6, jl = e & 63;
      t[kl][jl] = ldb(isbf, bw, (size_t)(k0 + kl) * 128 + j0 + jl);
    }
    __syncthreads();
    #pragma unroll
    for (int i = 0; i < 16; ++i) {
      int e = tid + 256 * i;
      int jl = e >> 6, kl = e & 63;
      bbT[(size_t)(j0 + jl) * 16448 + k0 + kl] = t[kl][jl];
    }
  } else {
    const int idx = b - 662;
    const int h = idx >> 1, i0 = (idx & 1) * 64;
    const void* W = (h == 0) ? f1w : (h == 1) ? f2w : (h == 2) ? taw : tbw;
    #pragma unroll
    for (int i = 0; i < 16; ++i) {
      int e = tid + 256 * i;
      int il = e >> 6, cl = e & 63;
      t[il][cl] = ldb(isbf, W, (i0 + il) * 64 + cl);
    }
    __syncthreads();
    #pragma unroll
    for (int i = 0; i < 16; ++i) {
      int e = tid + 256 * i;
      int cl = e >> 6, il = e & 63;
      HT[(h * 64 + cl) * 128 + i0 + il] = t[il][cl];
    }
  }
}

// ---------- fused conv1+conv2: one image per block (R0 structure) ----------
// LDS u32 map:
//   XS   @ 0     : 3 planes x 66 rows x 34 u32 (shifted-pair, rows 0/65 = 0)
//   ZS   @ 6732  : 68 u32 zeros (conv1 K-pad plane reads)
//   A1H  @ 6800  : 16 planes x 34 rows x 18 u32 (shifted-pair, rows 0/33 = 0)
//   total 16592 u32 = 66368 B  -> 2 blocks/CU
__global__ __launch_bounds__(512, 4)
void k_convs(const int* __restrict__ flagp, const void* __restrict__ x,
             const u16* __restrict__ w1p, const u16* __restrict__ w2c,
             const float* __restrict__ consts, u16* __restrict__ feats) {
  __shared__ u32 lx[16592];
  const int isbf = *flagp;
  const int n = blockIdx.x;
  const int tid = threadIdx.x;
  const int wv = tid >> 6, lane = tid & 63, quad = lane >> 4, l15 = lane & 15;

  // zero: xs border rows + zero strip + whole a1h (disjoint from staging)
  for (int e = tid; e < 10064; e += 512) {
    int idx;
    if (e < 204) {
      const int pl = e / 68;
      const int rem = e - pl * 68;
      const int r = rem / 34;
      idx = pl * 2244 + r * (65 * 34) + (rem - r * 34);
    } else if (e < 272) {
      idx = 6732 + (e - 204);
    } else {
      idx = 6800 + (e - 272);
    }
    lx[idx] = 0u;
  }
  // stage x -> XS (interior rows 1..64), shifted-pair bf16
  for (int e = tid; e < 3072; e += 512) {
    const int ci = e >> 10;
    const int rr = (e >> 4) & 63;
    const int tt = e & 15;
    u32* dst = &lx[(ci * 66 + rr + 1) * 34];
    if (!isbf) {
      const float* src = (const float*)x + (((size_t)n * 3 + ci) * 64 + rr) * 64 + 4 * tt;
      const f32x4 v = *(const f32x4*)src;
      const float pv = tt ? src[-1] : 0.f;
      dst[2 * tt]     = (u32)f2bf(pv)   | (((u32)f2bf(v[0])) << 16);
      dst[2 * tt + 1] = (u32)f2bf(v[1]) | (((u32)f2bf(v[2])) << 16);
      if (tt == 15) { dst[32] = (u32)f2bf(v[3]); dst[33] = 0u; }
    } else {
      const u16* src = (const u16*)x + (((size_t)n * 3 + ci) * 64 + rr) * 64 + 4 * tt;
      const u16 pv = tt ? src[-1] : (u16)0;
      dst[2 * tt]     = (u32)pv | (((u32)src[0]) << 16);
      dst[2 * tt + 1] = (u32)src[1] | (((u32)src[2]) << 16);
      if (tt == 15) { dst[32] = (u32)src[3]; dst[33] = 0u; }
    }
  }
  __syncthreads();

  f32x4 acc2[8];
  #pragma unroll
  for (int rr = 0; rr < 8; ++rr) acc2[rr] = f32x4{0.f, 0.f, 0.f, 0.f};

  const int khb = (quad & 1) * 2;
  const int cih = quad >> 1;
  const int mt = wv & 3;    // conv2: co-group
  const int og = wv >> 2;   // conv2: oh-octet (oh = og*8 + rr)
  u16* lp = (u16*)lx;

  #pragma unroll
  for (int h = 0; h < 2; ++h) {
    // ---- conv1 half: co = h*16 .. h*16+15 -> A1H ----
    const s16x8 af0 = *(const s16x8*)(w1p + (h * 16 + l15) * 64 + quad * 8);
    const s16x8 af1 = *(const s16x8*)(w1p + (h * 16 + l15) * 64 + 32 + quad * 8);
    #pragma unroll
    for (int i = 0; i < 8; ++i) {
      const int nt = wv * 8 + i;
      const int oh = nt >> 1;
      const int ob = (nt & 1) * 16;
      f32x4 a1acc = f32x4{0.f, 0.f, 0.f, 0.f};
      {
        const int base = (cih * 66 + 2 * oh + khb) * 34 + ob + l15;
        union { u32 u[4]; s16x8 v; } bf;
        bf.u[0] = lx[base];
        bf.u[1] = lx[base + 1];
        bf.u[2] = lx[base + 34];
        bf.u[3] = lx[base + 35];
        a1acc = mfma16x16x32(af0, bf.v, a1acc);
      }
      {
        const int ci1 = 2 + cih;  // 2 or 3 (3 = K-pad -> zero strip)
        const int base = (ci1 < 3) ? ((ci1 * 66 + 2 * oh + khb) * 34 + ob + l15)
                                   : (6732 + ob + l15);
        union { u32 u[4]; s16x8 v; } bf;
        bf.u[0] = lx[base];
        bf.u[1] = lx[base + 1];
        bf.u[2] = lx[base + 34];
        bf.u[3] = lx[base + 35];
        a1acc = mfma16x16x32(af1, bf.v, a1acc);
      }
      #pragma unroll
      for (int r = 0; r < 4; ++r) {
        const int co = quad * 4 + r;
        float v = a1acc[r] + consts[h * 16 + co];
        v = v > 0.f ? v : 0.f;
        lp[(6800 + (co * 34 + oh + 1) * 18) * 2 + ob + l15 + 1] = f2bf(v);
      }
    }
    __syncthreads();  // a1 half ready
    // ---- conv2 K-half: planes 16h..16h+15 ----
    // wave remap: ONE w2c fragment per kst (mt fixed), 8 MFMA vs a1 rows.
    #pragma unroll
    for (int kst = 0; kst < 8; ++kst) {
      const int kglob = h * 8 + kst;
      const s16x8 afr =
          *(const s16x8*)(w2c + (mt * 16 + l15) * 512 + kglob * 32 + quad * 8);
      const int ci = kst * 2 + cih;
      #pragma unroll
      for (int rr = 0; rr < 8; ++rr) {
        const int row1 = 2 * (og * 8 + rr) + khb;
        const int base = 6800 + (ci * 34 + row1) * 18 + l15;
        union { u32 u[4]; s16x8 v; } bf;
        bf.u[0] = lx[base];
        bf.u[1] = lx[base + 1];
        bf.u[2] = lx[base + 18];
        bf.u[3] = lx[base + 19];
        acc2[rr] = mfma16x16x32(afr, bf.v, acc2[rr]);
      }
    }
    if (h == 0) __syncthreads();  // conv2 h0 done reading before conv1 h1 writes
  }
  // ---- epilogue: feats ----
  #pragma unroll
  for (int rr = 0; rr < 8; ++rr) {
    const int oh = og * 8 + rr;
    #pragma unroll
    for (int r = 0; r < 4; ++r) {
      const int co = mt * 16 + quad * 4 + r;
      const float bias = consts[32 + co];
      float v = acc2[rr][r] + bias;
      v = v > 0.f ? v : 0.f;
      feats[(size_t)n * 16384 + co * 256 + oh * 16 + l15] = f2bf(v);
    }
  }
}

// ---------- xb partials: feats @ bb_w[:16384], split-K=16, NO atomics ------
__global__ __launch_bounds__(256)
void k_xb(const u16* __restrict__ feats, const u16* __restrict__ bbT,
          float* __restrict__ xbp) {
  const int m0 = blockIdx.x * 64;
  const int kc = blockIdx.y;
  const int kc0 = kc * 1024;
  const int tid = threadIdx.x;
  const int w = tid >> 6, lane = tid & 63, quad = lane >> 4, l15 = lane & 15;
  f32x4 acc[4][2];
  #pragma unroll
  for (int mt = 0; mt < 4; ++mt)
    #pragma unroll
    for (int i = 0; i < 2; ++i) acc[mt][i] = f32x4{0.f, 0.f, 0.f, 0.f};
  #pragma unroll 4
  for (int kst = 0; kst < 32; ++kst) {
    const int k = kc0 + kst * 32 + quad * 8;
    s16x8 afrag[4], bfrag[2];
    #pragma unroll
    for (int mt = 0; mt < 4; ++mt)
      afrag[mt] = *(const s16x8*)(feats + (size_t)(m0 + mt * 16 + l15) * 16384 + k);
    #pragma unroll
    for (int i = 0; i < 2; ++i)
      bfrag[i] = *(const s16x8*)(bbT + (size_t)((w * 2 + i) * 16 + l15) * 16448 + k);
    #pragma unroll
    for (int mt = 0; mt < 4; ++mt)
      #pragma unroll
      for (int i = 0; i < 2; ++i)
        acc[mt][i] = mfma16x16x32(afrag[mt], bfrag[i], acc[mt][i]);
  }
  float* dst = xbp + (size_t)kc * 262144;
  #pragma unroll
  for (int mt = 0; mt < 4; ++mt)
    #pragma unroll
    for (int i = 0; i < 2; ++i) {
      const int j = (w * 2 + i) * 16 + l15;
      #pragma unroll
      for (int r = 0; r < 4; ++r) {
        const int m = m0 + mt * 16 + quad * 4 + r;
        dst[m * 128 + j] = acc[mt][i][r];
      }
    }
}

// ---------- reduce split-K partials -> xb ----------
__global__ __launch_bounds__(256)
void k_xbsum(const float* __restrict__ xbp, float* __restrict__ xb) {
  const int e = blockIdx.x * 256 + threadIdx.x;
  float s = 0.f;
  #pragma unroll
  for (int kc = 0; kc < 16; ++kc) s += xbp[(size_t)kc * 262144 + e];
  xb[e] = s;
}

// ---------- CfC recurrence: one block per batch row, 3 barriers/step ----------
__global__ __launch_bounds__(256)
void k_rec(const int* __restrict__ flagp, const float* __restrict__ xb,
           const u16* __restrict__ bbT, const u16* __restrict__ HT,
           const float* __restrict__ consts, float* __restrict__ rout,
           void* __restrict__ outv) {
  __shared__ float xbl[64 * 128];
  __shared__ float h[64];
  __shared__ float bbv[128];
  __shared__ float heads[256];
  const int isbf = *flagp;
  const int b = blockIdx.x;
  const int tid = threadIdx.x;
  {
    const float* src = xb + (size_t)b * 64 * 128;
    #pragma unroll
    for (int q = 0; q < 32; ++q) xbl[q * 256 + tid] = src[q * 256 + tid];
  }
  // phase-1 weights: full K=64 column for j = tid (threads 0..127)
  float w1r[64];
  if (tid < 128) {
    const u32* src = (const u32*)(bbT + (size_t)tid * 16448 + 16384);
    #pragma unroll
    for (int q = 0; q < 32; ++q) bf2x2(src[q], w1r[2 * q], w1r[2 * q + 1]);
  }
  float w2r[128];
  {
    const u32* src = (const u32*)(HT + tid * 128);
    #pragma unroll
    for (int q = 0; q < 64; ++q) bf2x2(src[q], w2r[2 * q], w2r[2 * q + 1]);
  }
  const float hbias = consts[224 + tid];
  const float bbias = (tid < 128) ? consts[96 + tid] : 0.f;
  if (tid < 64) h[tid] = consts[1000 + b * 64 + tid];
  __syncthreads();
  for (int t = 0; t < 64; ++t) {
    if (tid < 128) {
      float p0 = 0.f, p1 = 0.f, p2 = 0.f, p3 = 0.f;
      #pragma unroll
      for (int q = 0; q < 16; ++q) {
        p0 += h[4 * q + 0] * w1r[4 * q + 0];
        p1 += h[4 * q + 1] * w1r[4 * q + 1];
        p2 += h[4 * q + 2] * w1r[4 * q + 2];
        p3 += h[4 * q + 3] * w1r[4 * q + 3];
      }
      const float s = (p0 + p1) + (p2 + p3) + xbl[t * 128 + tid] + bbias;
      bbv[tid] = 1.7159f * fast_tanh(0.666f * s);
    }
    __syncthreads();
    float c0 = 0.f, c1 = 0.f, c2 = 0.f, c3 = 0.f;
    #pragma unroll
    for (int q = 0; q < 32; ++q) {
      c0 += bbv[4 * q + 0] * w2r[4 * q + 0];
      c1 += bbv[4 * q + 1] * w2r[4 * q + 1];
      c2 += bbv[4 * q + 2] * w2r[4 * q + 2];
      c3 += bbv[4 * q + 3] * w2r[4 * q + 3];
    }
    heads[tid] = (c0 + c1) + (c2 + c3) + hbias;
    __syncthreads();
    if (tid < 64) {
      const float ff1 = fast_tanh(heads[tid]);
      const float ff2 = fast_tanh(heads[64 + tid]);
      const float ti = 1.f / (1.f + __expf(-(heads[128 + tid] + heads[192 + tid])));
      const float hn = ff1 * (1.f - ti) + ti * ff2;
      h[tid] = hn;
      rout[((size_t)b * 64 + t) * 64 + tid] = hn;
    }
    __syncthreads();
  }
  if (tid < 64) {
    if (isbf) ((u16*)outv)[16384 + b * 64 + tid] = f2bf(h[tid]);
    else      ((float*)outv)[16384 + b * 64 + tid] = h[tid];
  }
}

// ---------- logits = rout @ out_w + out_b ----------
__global__ __launch_bounds__(256)
void k_logits(const int* __restrict__ flagp, const float* __restrict__ rout,
              const float* __restrict__ consts, void* __restrict__ outv) {
  __shared__ float W[512];
  __shared__ float Bv[8];
  const int isbf = *flagp;
  const int tid = threadIdx.x;
  for (int e = tid; e < 512; e += 256) W[e] = consts[480 + e];
  if (tid < 8) Bv[tid] = consts[992 + tid];
  __syncthreads();
  const int bt = blockIdx.x * 256 + tid;
  float acc[8];
  #pragma unroll
  for (int c = 0; c < 8; ++c) acc[c] = Bv[c];
  const f32x4* r = (const f32x4*)(rout + (size_t)bt * 64);
  #pragma unroll
  for (int q = 0; q < 16; ++q) {
    f32x4 v = r[q];
    #pragma unroll
    for (int u = 0; u < 4; ++u) {
      const float rv = v[u];
      const int i = 4 * q + u;
      #pragma unroll
      for (int c = 0; c < 8; ++c) acc[c] += rv * W[i * 8 + c];
    }
  }
  if (isbf) {
    u32 pk[4];
    #pragma unroll
    for (int c = 0; c < 4; ++c)
      pk[c] = (u32)f2bf(acc[2 * c]) | ((u32)f2bf(acc[2 * c + 1]) << 16);
    *(uint4*)((u16*)outv + (size_t)bt * 8) = *(const uint4*)pk;
  } else {
    float* o = (float*)outv + (size_t)bt * 8;
    *(f32x4*)o = f32x4{acc[0], acc[1], acc[2], acc[3]};
    *(f32x4*)(o + 4) = f32x4{acc[4], acc[5], acc[6], acc[7]};
  }
}

extern "C" void kernel_launch(void* const* d_in, const int* in_sizes, int n_in,
                              void* d_out, int out_size, void* d_ws, size_t ws_size,
                              hipStream_t stream) {
  const void* x   = d_in[0];
  const void* hx  = d_in[1];
  const void* w1  = d_in[2];
  const void* b1  = d_in[3];
  const void* w2  = d_in[4];
  const void* b2  = d_in[5];
  const void* bbw = d_in[6];
  const void* bbb = d_in[7];
  const void* f1w = d_in[8];
  const void* f1b = d_in[9];
  const void* f2w = d_in[10];
  const void* f2b = d_in[11];
  const void* taw = d_in[12];
  const void* tab = d_in[13];
  const void* tbw = d_in[14];
  const void* tbb = d_in[15];
  const void* oww = d_in[16];
  const void* obb = d_in[17];

  char* ws = (char*)d_ws;
  float* xbp   = (float*)(ws);
  u16*   feats = (u16*)(ws + 150994944);
  u16*   bbT   = (u16*)(ws + 218103808);
  u16*   HT    = (u16*)(ws + 222314496);
  u16*   w1p   = (u16*)(ws + 222380032);
  u16*   w2c   = (u16*)(ws + 222384128);
  float* xb    = (float*)(ws + 222449664);
  float* rout  = (float*)(ws + 223498240);
  float* consts= (float*)(ws + 224022528);
  int*   flag  = (int*)(ws + 224034816);

  k_prep_all<<<670, 256, 0, stream>>>((const u32*)bbw, b1, b2, bbb, f1b, f2b,
                                      tab, tbb, oww, obb, hx, w1, w2, bbw,
                                      f1w, f2w, taw, tbw,
                                      consts, w1p, w2c, bbT, HT, flag);
  k_convs<<<2048, 512, 0, stream>>>(flag, x, w1p, w2c, consts, feats);
  k_xb<<<dim3(32, 16), 256, 0, stream>>>(feats, bbT, xbp);
  k_xbsum<<<1024, 256, 0, stream>>>(xbp, xb);
  k_rec<<<32, 256, 0, stream>>>(flag, xb, bbT, HT, consts, rout, d_out);
  k_logits<<<8, 256, 0, stream>>>(flag, rout, consts, d_out);
}